// Round 1
// baseline (215.459 us; speedup 1.0000x reference)
//
#include <hip/hip_runtime.h>

// Performer causal linear attention (generalized relu kernel), fp32.
// B=1, H=8, N=1024, D=64, M=128. Chunked formulation, chunk C=128:
//   qp = relu(norm * q @ proj^T) + eps ; kp likewise
//   Z  = cumsum_n kp ; W = qp / Z
//   out_c = W_c @ S0_c + tril(W_c @ Kp_c^T) @ V_c
//   S0_c  = sum_{c'<c} Kp_{c'}^T V_{c'}
static constexpr int H = 8, N = 1024, D = 64, M = 128, CHUNK = 128, NC = 8;
static constexpr float EPS = 1e-3f;
static constexpr float NORM = 0.35355339059327373f; // 64^-0.25

// ---------------------------------------------------------------- K1: qp/kp
// grid (N/32, H, 2), 256 thr. Block: 32 rows of q or k -> 32x128 outputs.
__global__ __launch_bounds__(256) void k_proj(const float* __restrict__ q,
                                              const float* __restrict__ k,
                                              const float* __restrict__ proj,
                                              float* __restrict__ qp,
                                              float* __restrict__ kp) {
    __shared__ float plT[64 * 132]; // [d][m], padded row 132 (16B-aligned)
    __shared__ float xlT[64 * 36];  // [d][r], 32 rows, padded row 36
    const int tid = threadIdx.x;
    const int rblk = blockIdx.x;
    const int h = blockIdx.y;
    const int which = blockIdx.z;
    const float* __restrict__ x = which ? k : q;
    float* __restrict__ o = which ? kp : qp;

    for (int i = tid; i < M * D; i += 256) {
        int m = i >> 6, d = i & 63;
        plT[d * 132 + m] = proj[i];
    }
    const int rowbase = h * N + rblk * 32;
    for (int i = tid; i < 32 * D; i += 256) {
        int r = i >> 6, d = i & 63;
        xlT[d * 36 + r] = x[(rowbase + r) * D + d] * NORM;
    }
    __syncthreads();

    const int m0 = (tid & 31) * 4;
    const int r0 = (tid >> 5) * 4;
    float acc[4][4] = {};
#pragma unroll 8
    for (int d = 0; d < 64; d++) {
        float4 xv = *(const float4*)&xlT[d * 36 + r0];
        float4 pv = *(const float4*)&plT[d * 132 + m0];
        const float xr[4] = {xv.x, xv.y, xv.z, xv.w};
        const float pr[4] = {pv.x, pv.y, pv.z, pv.w};
#pragma unroll
        for (int ri = 0; ri < 4; ri++)
#pragma unroll
            for (int mi = 0; mi < 4; mi++) acc[ri][mi] += xr[ri] * pr[mi];
    }
#pragma unroll
    for (int ri = 0; ri < 4; ri++) {
        float4 s;
        s.x = fmaxf(acc[ri][0], 0.f) + EPS;
        s.y = fmaxf(acc[ri][1], 0.f) + EPS;
        s.z = fmaxf(acc[ri][2], 0.f) + EPS;
        s.w = fmaxf(acc[ri][3], 0.f) + EPS;
        *(float4*)&o[(rowbase + r0 + ri) * M + m0] = s;
    }
}

// ------------------------------------------------- K2: G_c = Kp_c^T V_c, ksum
// grid 64 = (h,c), 256 thr. Also per-chunk column sums of kp (for Z bases).
__global__ __launch_bounds__(256) void k_gsum(const float* __restrict__ kp,
                                              const float* __restrict__ v,
                                              float* __restrict__ G,
                                              float* __restrict__ ksum) {
    __shared__ float kpl[32 * 128]; // [nn][m]
    __shared__ float vl[32 * 64];   // [nn][e]
    const int tid = threadIdx.x;
    const int b = blockIdx.x;
    const int h = b >> 3, c = b & 7;
    const int m0 = (tid >> 3) * 4, e0 = (tid & 7) * 8;
    float acc[4][8] = {};
    float ks = 0.f;
    for (int nc = 0; nc < 4; nc++) {
        const int n0 = c * CHUNK + nc * 32;
        for (int i = tid; i < 32 * 128; i += 256)
            kpl[i] = kp[(h * N + n0 + (i >> 7)) * M + (i & 127)];
        for (int i = tid; i < 32 * 64; i += 256)
            vl[i] = v[(h * N + n0 + (i >> 6)) * D + (i & 63)];
        __syncthreads();
#pragma unroll 4
        for (int nn = 0; nn < 32; nn++) {
            float4 kv = *(const float4*)&kpl[nn * 128 + m0];
            float4 va = *(const float4*)&vl[nn * 64 + e0];
            float4 vb = *(const float4*)&vl[nn * 64 + e0 + 4];
            const float kr[4] = {kv.x, kv.y, kv.z, kv.w};
            const float vr[8] = {va.x, va.y, va.z, va.w, vb.x, vb.y, vb.z, vb.w};
#pragma unroll
            for (int mi = 0; mi < 4; mi++)
#pragma unroll
                for (int ej = 0; ej < 8; ej++) acc[mi][ej] += kr[mi] * vr[ej];
        }
        if (tid < 128) {
#pragma unroll 8
            for (int nn = 0; nn < 32; nn++) ks += kpl[nn * 128 + tid];
        }
        __syncthreads();
    }
#pragma unroll
    for (int mi = 0; mi < 4; mi++) {
        float4 a = {acc[mi][0], acc[mi][1], acc[mi][2], acc[mi][3]};
        float4 bq = {acc[mi][4], acc[mi][5], acc[mi][6], acc[mi][7]};
        *(float4*)&G[(b * M + m0 + mi) * D + e0] = a;
        *(float4*)&G[(b * M + m0 + mi) * D + e0 + 4] = bq;
    }
    if (tid < 128) ksum[b * M + tid] = ks;
}

// ------------------------------------- K3: W = qp / Z  (in-place over qp)
// grid 64 = (h,c), 128 thr (one per m). Z = chunk-prefix base + local scan.
__global__ __launch_bounds__(128) void k_wdiv(float* __restrict__ qp,
                                              const float* __restrict__ kp,
                                              const float* __restrict__ ksum) {
    const int b = blockIdx.x;
    const int h = b >> 3, c = b & 7;
    const int m = threadIdx.x;
    float z = 0.f;
    for (int cp = 0; cp < c; cp++) z += ksum[(h * NC + cp) * M + m];
    int idx = (h * N + c * CHUNK) * M + m;
#pragma unroll 4
    for (int n = 0; n < CHUNK; n++, idx += M) {
        z += kp[idx];
        qp[idx] = qp[idx] * __builtin_amdgcn_rcpf(z);
    }
}

// ---------------------------------------- K3b: S0_c = sum_{c'<c} G_{c'}
__global__ __launch_bounds__(256) void k_s0(const float* __restrict__ G,
                                            float* __restrict__ S0) {
    const int b = blockIdx.x;
    const int h = b >> 3, c = b & 7;
    for (int i = threadIdx.x; i < M * D; i += 256) {
        float acc = 0.f;
        for (int cp = 0; cp < c; cp++) acc += G[(h * NC + cp) * (M * D) + i];
        S0[b * (M * D) + i] = acc;
    }
}

// ------------------------------- K4: A = tril(W_c @ Kp_c^T)  (incl. diag)
// grid (64, 2): (h,c) x n-half. 256 thr, each 4n x 8j outputs.
__global__ __launch_bounds__(256) void k_amat(const float* __restrict__ W,
                                              const float* __restrict__ kp,
                                              float* __restrict__ A) {
    __shared__ float Wt[32 * 68];  // [mm][n] 64 rows
    __shared__ float Kt[32 * 132]; // [mm][j] 128 cols
    const int tid = threadIdx.x;
    const int b = blockIdx.x;
    const int h = b >> 3, c = b & 7;
    const int half = blockIdx.y;
    const int n0 = (tid >> 4) * 4, j0 = (tid & 15) * 8;
    const int rowbase = h * N + c * CHUNK + half * 64;
    float acc[4][8] = {};
    for (int mc = 0; mc < 4; mc++) {
        const int m0 = mc * 32;
        for (int i = tid; i < 32 * 64; i += 256) {
            int mm = i & 31, n = i >> 5;
            Wt[mm * 68 + n] = W[(rowbase + n) * M + m0 + mm];
        }
        for (int i = tid; i < 32 * 128; i += 256) {
            int mm = i & 31, j = i >> 5;
            Kt[mm * 132 + j] = kp[(h * N + c * CHUNK + j) * M + m0 + mm];
        }
        __syncthreads();
#pragma unroll 8
        for (int mm = 0; mm < 32; mm++) {
            float4 wa = *(const float4*)&Wt[mm * 68 + n0];
            float4 ka = *(const float4*)&Kt[mm * 132 + j0];
            float4 kb = *(const float4*)&Kt[mm * 132 + j0 + 4];
            const float wr[4] = {wa.x, wa.y, wa.z, wa.w};
            const float jr[8] = {ka.x, ka.y, ka.z, ka.w, kb.x, kb.y, kb.z, kb.w};
#pragma unroll
            for (int ni = 0; ni < 4; ni++)
#pragma unroll
                for (int ji = 0; ji < 8; ji++) acc[ni][ji] += wr[ni] * jr[ji];
        }
        __syncthreads();
    }
    const int abase = b * (CHUNK * CHUNK);
#pragma unroll
    for (int ni = 0; ni < 4; ni++) {
        const int n = half * 64 + n0 + ni;
        float sv[8];
#pragma unroll
        for (int jj = 0; jj < 8; jj++) sv[jj] = (j0 + jj <= n) ? acc[ni][jj] : 0.f;
        float4 lo = {sv[0], sv[1], sv[2], sv[3]};
        float4 hi = {sv[4], sv[5], sv[6], sv[7]};
        *(float4*)&A[abase + n * CHUNK + j0] = lo;
        *(float4*)&A[abase + n * CHUNK + j0 + 4] = hi;
    }
}

// ----------------------- K5: out = [W | A] @ [S0 ; V]   (K = 128 + 128)
// grid (64, 2): (h,c) x n-half. 256 thr, each 4n x 4e outputs.
__global__ __launch_bounds__(256) void k_out(const float* __restrict__ W,
                                             const float* __restrict__ A,
                                             const float* __restrict__ S0,
                                             const float* __restrict__ v,
                                             float* __restrict__ out) {
    __shared__ float Ut[32 * 68]; // [kk][n] 64 rows
    __shared__ float Xs[32 * 68]; // [kk][e] 64 cols
    const int tid = threadIdx.x;
    const int b = blockIdx.x;
    const int h = b >> 3, c = b & 7;
    const int half = blockIdx.y;
    const int n0 = (tid >> 4) * 4, e0 = (tid & 15) * 4;
    const int rowbase = h * N + c * CHUNK + half * 64;
    float acc[4][4] = {};
    for (int kc = 0; kc < 8; kc++) {
        const int k0 = kc * 32;
        if (kc < 4) {
            for (int i = tid; i < 2048; i += 256) {
                int kk = i & 31, n = i >> 5;
                Ut[kk * 68 + n] = W[(rowbase + n) * M + k0 + kk];
            }
            for (int i = tid; i < 2048; i += 256) {
                int kk = i >> 6, e = i & 63;
                Xs[kk * 68 + e] = S0[b * (M * D) + (k0 + kk) * D + e];
            }
        } else {
            for (int i = tid; i < 2048; i += 256) {
                int kk = i & 31, n = i >> 5;
                Ut[kk * 68 + n] =
                    A[b * (CHUNK * CHUNK) + (half * 64 + n) * CHUNK + (k0 - 128 + kk)];
            }
            for (int i = tid; i < 2048; i += 256) {
                int kk = i >> 6, e = i & 63;
                Xs[kk * 68 + e] = v[(h * N + c * CHUNK + (k0 - 128 + kk)) * D + e];
            }
        }
        __syncthreads();
#pragma unroll 8
        for (int kk = 0; kk < 32; kk++) {
            float4 uu = *(const float4*)&Ut[kk * 68 + n0];
            float4 xx = *(const float4*)&Xs[kk * 68 + e0];
            const float ur[4] = {uu.x, uu.y, uu.z, uu.w};
            const float xr[4] = {xx.x, xx.y, xx.z, xx.w};
#pragma unroll
            for (int ni = 0; ni < 4; ni++)
#pragma unroll
                for (int ei = 0; ei < 4; ei++) acc[ni][ei] += ur[ni] * xr[ei];
        }
        __syncthreads();
    }
#pragma unroll
    for (int ni = 0; ni < 4; ni++) {
        float4 s = {acc[ni][0], acc[ni][1], acc[ni][2], acc[ni][3]};
        *(float4*)&out[(rowbase + n0 + ni) * D + e0] = s;
    }
}

extern "C" void kernel_launch(void* const* d_in, const int* in_sizes, int n_in,
                              void* d_out, int out_size, void* d_ws, size_t ws_size,
                              hipStream_t stream) {
    const float* q = (const float*)d_in[0];
    const float* k = (const float*)d_in[1];
    const float* v = (const float*)d_in[2];
    const float* proj = (const float*)d_in[3];
    float* out = (float*)d_out;

    // workspace layout (floats): total 4,202,496 floats = 16.8 MB
    float* ws = (float*)d_ws;
    float* qp = ws;                  // H*N*M, becomes W after k_wdiv
    float* kp = qp + H * N * M;      // H*N*M
    float* ksum = kp + H * N * M;    // H*NC*M
    float* G = ksum + H * NC * M;    // H*NC*M*D
    float* S0 = G + H * NC * M * D;  // H*NC*M*D
    float* A = S0 + H * NC * M * D;  // H*NC*CHUNK*CHUNK

    k_proj<<<dim3(N / 32, H, 2), 256, 0, stream>>>(q, k, proj, qp, kp);
    k_gsum<<<H * NC, 256, 0, stream>>>(kp, v, G, ksum);
    k_wdiv<<<H * NC, 128, 0, stream>>>(qp, kp, ksum);
    k_s0<<<H * NC, 256, 0, stream>>>(G, S0);
    k_amat<<<dim3(H * NC, 2), 256, 0, stream>>>(qp, kp, A);
    k_out<<<dim3(H * NC, 2), 256, 0, stream>>>(qp, A, S0, v, out);
}

// Round 3
// 133.389 us; speedup vs baseline: 1.6153x; 1.6153x over previous
//
#include <hip/hip_runtime.h>

// Performer causal linear attention (generalized relu kernel), fp32.
// B=1, H=8, N=1024, D=64, M=128. Chunked formulation, chunk C=128:
//   qp = relu(norm * q @ proj^T) + eps ; kp likewise
//   Z  = cumsum_n kp ; W = qp / Z
//   out_c = W_c @ S0_c + tril(W_c @ Kp_c^T) @ V_c
//   S0_c  = sum_{c'<c} Kp_{c'}^T V_{c'}
// R3: same structure as R2 with k_wdiv thread-count bug fixed (256 thr,
// seg in {0,1} — 512 thr made seg 0..3 and stomped neighboring chunks).
static constexpr int H = 8, N = 1024, D = 64, M = 128, CHUNK = 128, NC = 8;
static constexpr float EPS = 1e-3f;
static constexpr float NORM = 0.35355339059327373f; // 64^-0.25

// ---------------------------------------------------------------- K1: qp/kp
// grid (N/32, H, 2), 256 thr. Block: 32 rows of q or k -> 32x128 outputs.
__global__ __launch_bounds__(256) void k_proj(const float* __restrict__ q,
                                              const float* __restrict__ k,
                                              const float* __restrict__ proj,
                                              float* __restrict__ qp,
                                              float* __restrict__ kp) {
    __shared__ float plT[64 * 132]; // [d][m], padded row 132 (16B-aligned)
    __shared__ float xlT[64 * 36];  // [d][r], 32 rows
    const int tid = threadIdx.x;
    const int rblk = blockIdx.x;
    const int h = blockIdx.y;
    const int which = blockIdx.z;
    const float* __restrict__ x = which ? k : q;
    float* __restrict__ o = which ? kp : qp;

    for (int i = tid; i < M * D; i += 256) {
        int m = i >> 6, d = i & 63;
        plT[d * 132 + m] = proj[i];
    }
    const int rowbase = h * N + rblk * 32;
    for (int i = tid; i < 32 * D; i += 256) {
        int r = i >> 6, d = i & 63;
        xlT[d * 36 + r] = x[(rowbase + r) * D + d] * NORM;
    }
    __syncthreads();

    const int m0 = (tid & 31) * 4;
    const int r0 = (tid >> 5) * 4;
    float acc[4][4] = {};
#pragma unroll 8
    for (int d = 0; d < 64; d++) {
        float4 xv = *(const float4*)&xlT[d * 36 + r0];
        float4 pv = *(const float4*)&plT[d * 132 + m0];
        const float xr[4] = {xv.x, xv.y, xv.z, xv.w};
        const float pr[4] = {pv.x, pv.y, pv.z, pv.w};
#pragma unroll
        for (int ri = 0; ri < 4; ri++)
#pragma unroll
            for (int mi = 0; mi < 4; mi++) acc[ri][mi] += xr[ri] * pr[mi];
    }
#pragma unroll
    for (int ri = 0; ri < 4; ri++) {
        float4 s;
        s.x = fmaxf(acc[ri][0], 0.f) + EPS;
        s.y = fmaxf(acc[ri][1], 0.f) + EPS;
        s.z = fmaxf(acc[ri][2], 0.f) + EPS;
        s.w = fmaxf(acc[ri][3], 0.f) + EPS;
        *(float4*)&o[(rowbase + r0 + ri) * M + m0] = s;
    }
}

// ------------------------------------ K2: G partials = Kp_seg^T V_seg, ksum
// grid (H*NC, 2), 256 thr. Each block: 64 rows -> G_part[b*2+p][M][D],
// ksum_part[b*2+p][M].
__global__ __launch_bounds__(256) void k_gsum(const float* __restrict__ kp,
                                              const float* __restrict__ v,
                                              float* __restrict__ Gp,
                                              float* __restrict__ kpart) {
    __shared__ float kpl[32 * 128]; // [nn][m]
    __shared__ float vl[32 * 64];   // [nn][e]
    const int tid = threadIdx.x;
    const int b = blockIdx.x;
    const int p = blockIdx.y;
    const int h = b >> 3, c = b & 7;
    const int m0 = (tid >> 3) * 4, e0 = (tid & 7) * 8;
    float acc[4][8] = {};
    float ks = 0.f;
    for (int nc = 0; nc < 2; nc++) {
        const int n0 = c * CHUNK + p * 64 + nc * 32;
        for (int i = tid; i < 32 * 128; i += 256)
            kpl[i] = kp[(h * N + n0 + (i >> 7)) * M + (i & 127)];
        for (int i = tid; i < 32 * 64; i += 256)
            vl[i] = v[(h * N + n0 + (i >> 6)) * D + (i & 63)];
        __syncthreads();
#pragma unroll 4
        for (int nn = 0; nn < 32; nn++) {
            float4 kv = *(const float4*)&kpl[nn * 128 + m0];
            float4 va = *(const float4*)&vl[nn * 64 + e0];
            float4 vb = *(const float4*)&vl[nn * 64 + e0 + 4];
            const float kr[4] = {kv.x, kv.y, kv.z, kv.w};
            const float vr[8] = {va.x, va.y, va.z, va.w, vb.x, vb.y, vb.z, vb.w};
#pragma unroll
            for (int mi = 0; mi < 4; mi++)
#pragma unroll
                for (int ej = 0; ej < 8; ej++) acc[mi][ej] += kr[mi] * vr[ej];
        }
        if (tid < 128) {
#pragma unroll 8
            for (int nn = 0; nn < 32; nn++) ks += kpl[nn * 128 + tid];
        }
        __syncthreads();
    }
    const int gb = b * 2 + p;
#pragma unroll
    for (int mi = 0; mi < 4; mi++) {
        float4 a = {acc[mi][0], acc[mi][1], acc[mi][2], acc[mi][3]};
        float4 bq = {acc[mi][4], acc[mi][5], acc[mi][6], acc[mi][7]};
        *(float4*)&Gp[(gb * M + m0 + mi) * D + e0] = a;
        *(float4*)&Gp[(gb * M + m0 + mi) * D + e0 + 4] = bq;
    }
    if (tid < 128) kpart[gb * M + tid] = ks;
}

// ------------------------- K3: S0 = exclusive chunk-prefix of G (single pass)
// grid (H, 16), 256 thr. Each block: 512 contiguous i of the 8192 per head.
__global__ __launch_bounds__(256) void k_scan(const float* __restrict__ Gp,
                                              float* __restrict__ S0) {
    const int h = blockIdx.x;
    const int i = blockIdx.y * 512 + threadIdx.x * 2;
    float r0 = 0.f, r1 = 0.f;
#pragma unroll
    for (int c = 0; c < NC; c++) {
        const int gb = h * NC + c;
        float2 s = {r0, r1};
        *(float2*)&S0[gb * (M * D) + i] = s;
        float2 a = *(const float2*)&Gp[(gb * 2 + 0) * (M * D) + i];
        float2 b = *(const float2*)&Gp[(gb * 2 + 1) * (M * D) + i];
        r0 += a.x + b.x;
        r1 += a.y + b.y;
    }
}

// ------------------------------------- K4: W = qp / Z  (in-place over qp)
// grid 64, 256 thr: seg = tid>>7 in {0,1} picks the 64-row half of the chunk;
// serial scan length 64. (R2 bug: 512 thr gave seg in 0..3 -> cross-chunk
// stomp.)
__global__ __launch_bounds__(256) void k_wdiv(float* __restrict__ qp,
                                              const float* __restrict__ kp,
                                              const float* __restrict__ kpart) {
    const int b = blockIdx.x;
    const int h = b >> 3, c = b & 7;
    const int seg = threadIdx.x >> 7; // 0 or 1
    const int m = threadIdx.x & 127;
    float z = 0.f;
    for (int cp = 0; cp < c; cp++)
        z += kpart[((h * NC + cp) * 2 + 0) * M + m] +
             kpart[((h * NC + cp) * 2 + 1) * M + m];
    if (seg) z += kpart[(b * 2 + 0) * M + m];
    int idx = (h * N + c * CHUNK + seg * 64) * M + m;
#pragma unroll 4
    for (int n = 0; n < 64; n++, idx += M) {
        z += kp[idx];
        qp[idx] = qp[idx] * __builtin_amdgcn_rcpf(z);
    }
}

// -------------- K5 (fused): A = tril(W_c @ Kp_c^T) in LDS; out = W@S0 + A@V
// grid (H*NC, 2): (h,c) x 64-row half. 256 thr.
__global__ __launch_bounds__(256) void k_attn(const float* __restrict__ W,
                                              const float* __restrict__ kp,
                                              const float* __restrict__ S0,
                                              const float* __restrict__ v,
                                              float* __restrict__ out) {
    __shared__ float AT[128 * 68]; // [j][n] transposed A, padded
    __shared__ float Ut[32 * 68];  // [kk][n]
    __shared__ float Kt[32 * 132]; // [mm][j] phase1 / aliased Xs phase2
    float* Xs = Kt;                // [kk][e] phase2 (32*68 <= 32*132)
    const int tid = threadIdx.x;
    const int b = blockIdx.x;
    const int h = b >> 3, c = b & 7;
    const int half = blockIdx.y;
    const int rowbase = h * N + c * CHUNK + half * 64;
    const int n0 = (tid >> 4) * 4;

    // ---- phase 1: A = tril(W_half @ kp_c^T), 64n x 128j -> AT[j][n]
    {
        const int j0 = (tid & 15) * 8;
        float acc[4][8] = {};
        for (int mc = 0; mc < 4; mc++) {
            const int m0 = mc * 32;
            for (int i = tid; i < 32 * 64; i += 256) {
                int mm = i & 31, n = i >> 5;
                Ut[mm * 68 + n] = W[(rowbase + n) * M + m0 + mm];
            }
            for (int i = tid; i < 32 * 128; i += 256) {
                int mm = i & 31, j = i >> 5;
                Kt[mm * 132 + j] = kp[(h * N + c * CHUNK + j) * M + m0 + mm];
            }
            __syncthreads();
#pragma unroll 8
            for (int mm = 0; mm < 32; mm++) {
                float4 wa = *(const float4*)&Ut[mm * 68 + n0];
                float4 ka = *(const float4*)&Kt[mm * 132 + j0];
                float4 kb = *(const float4*)&Kt[mm * 132 + j0 + 4];
                const float wr[4] = {wa.x, wa.y, wa.z, wa.w};
                const float jr[8] = {ka.x, ka.y, ka.z, ka.w, kb.x, kb.y, kb.z, kb.w};
#pragma unroll
                for (int ni = 0; ni < 4; ni++)
#pragma unroll
                    for (int ji = 0; ji < 8; ji++) acc[ni][ji] += wr[ni] * jr[ji];
            }
            __syncthreads();
        }
        // masked write into AT[j][n]
#pragma unroll
        for (int jj = 0; jj < 8; jj++) {
            const int j = j0 + jj;
            float4 s;
            s.x = (j <= half * 64 + n0 + 0) ? acc[0][jj] : 0.f;
            s.y = (j <= half * 64 + n0 + 1) ? acc[1][jj] : 0.f;
            s.z = (j <= half * 64 + n0 + 2) ? acc[2][jj] : 0.f;
            s.w = (j <= half * 64 + n0 + 3) ? acc[3][jj] : 0.f;
            *(float4*)&AT[j * 68 + n0] = s;
        }
    }

    // ---- phase 2: out = W @ S0 (K=128) + A @ V (K=128)
    {
        const int e0 = (tid & 15) * 4;
        float acc[4][4] = {};
        for (int kc = 0; kc < 8; kc++) {
            __syncthreads(); // previous tile consumed / AT writes visible
            if (kc < 4) {
                const int k0 = kc * 32;
                for (int i = tid; i < 2048; i += 256) {
                    int kk = i & 31, n = i >> 5;
                    Ut[kk * 68 + n] = W[(rowbase + n) * M + k0 + kk];
                }
                for (int i = tid; i < 2048; i += 256) {
                    int kk = i >> 6, e = i & 63;
                    Xs[kk * 68 + e] = S0[b * (M * D) + (k0 + kk) * D + e];
                }
            } else {
                const int k0 = (kc - 4) * 32;
                for (int i = tid; i < 2048; i += 256) {
                    int kk = i >> 6, e = i & 63;
                    Xs[kk * 68 + e] = v[(h * N + c * CHUNK + k0 + kk) * D + e];
                }
            }
            __syncthreads();
            const float* ubase = (kc < 4) ? Ut : &AT[(kc - 4) * 32 * 68];
#pragma unroll 8
            for (int kk = 0; kk < 32; kk++) {
                float4 uu = *(const float4*)&ubase[kk * 68 + n0];
                float4 xx = *(const float4*)&Xs[kk * 68 + e0];
                const float ur[4] = {uu.x, uu.y, uu.z, uu.w};
                const float xr[4] = {xx.x, xx.y, xx.z, xx.w};
#pragma unroll
                for (int ni = 0; ni < 4; ni++)
#pragma unroll
                    for (int ei = 0; ei < 4; ei++) acc[ni][ei] += ur[ni] * xr[ei];
            }
        }
#pragma unroll
        for (int ni = 0; ni < 4; ni++) {
            float4 s = {acc[ni][0], acc[ni][1], acc[ni][2], acc[ni][3]};
            *(float4*)&out[(rowbase + n0 + ni) * D + e0] = s;
        }
    }
}

extern "C" void kernel_launch(void* const* d_in, const int* in_sizes, int n_in,
                              void* d_out, int out_size, void* d_ws, size_t ws_size,
                              hipStream_t stream) {
    const float* q = (const float*)d_in[0];
    const float* k = (const float*)d_in[1];
    const float* v = (const float*)d_in[2];
    const float* proj = (const float*)d_in[3];
    float* out = (float*)d_out;

    // workspace layout (floats): total ~3.69M floats = 14.1 MB
    float* ws = (float*)d_ws;
    float* qp = ws;                      // H*N*M (becomes W after k_wdiv)
    float* kp = qp + H * N * M;          // H*N*M
    float* kpart = kp + H * N * M;       // H*NC*2*M
    float* Gp = kpart + H * NC * 2 * M;  // H*NC*2*M*D
    float* S0 = Gp + H * NC * 2 * M * D; // H*NC*M*D

    k_proj<<<dim3(N / 32, H, 2), 256, 0, stream>>>(q, k, proj, qp, kp);
    k_gsum<<<dim3(H * NC, 2), 256, 0, stream>>>(kp, v, Gp, kpart);
    k_scan<<<dim3(H, 16), 256, 0, stream>>>(Gp, S0);
    k_wdiv<<<H * NC, 256, 0, stream>>>(qp, kp, kpart);
    k_attn<<<dim3(H * NC, 2), 256, 0, stream>>>(qp, kp, S0, v, out);
}

// Round 4
// 120.972 us; speedup vs baseline: 1.7811x; 1.1026x over previous
//
#include <hip/hip_runtime.h>

// Performer causal linear attention (generalized relu kernel), fp32.
// B=1, H=8, N=1024, D=64, M=128. Chunked formulation, chunk C=128:
//   qp = relu(norm * q @ proj^T) + eps ; kp likewise
//   Z  = cumsum_n kp ; W = qp / Z
//   out_c = W_c @ S0_c + tril(W_c @ Kp_c^T) @ V_c
//   S0_c  = sum_{c'<c} Kp_{c'}^T V_{c'}
// R4: latency-bound fixes. (1) k_gsum fused into k_proj's k-side (32-row G
// partials, 4 per chunk). (2) S0 prefix written in-place over Gp seg-0 slots.
// (3) k_wdiv: 128 blocks, serial 32. (4) k_attn: 512 thr, grid (64,2,2) with
// e-split phase2 (phase1 duplicated) -> 256 blocks, 8 waves/CU.
static constexpr int H = 8, N = 1024, D = 64, M = 128, CHUNK = 128, NC = 8;
static constexpr float EPS = 1e-3f;
static constexpr float NORM = 0.35355339059327373f; // 64^-0.25

// -------------------------------- K1: qp/kp (+ fused G/ksum on k-side)
// grid (N/32, H, 2), 256 thr. Block: 32 rows -> 32x128 qp or kp outputs;
// k-side additionally computes Gp[h*32+rblk][M][D] and kpart[h*32+rblk][M].
__global__ __launch_bounds__(256) void k_projg(const float* __restrict__ q,
                                               const float* __restrict__ k,
                                               const float* __restrict__ proj,
                                               const float* __restrict__ v,
                                               float* __restrict__ qp,
                                               float* __restrict__ kp,
                                               float* __restrict__ Gp,
                                               float* __restrict__ kpart) {
    __shared__ float plT[64 * 132]; // [d][m]; k-side reuses as kpl[32][132]
    __shared__ float xlT[64 * 36];  // [d][r]; k-side reuses as vl[32][68]
    const int tid = threadIdx.x;
    const int rblk = blockIdx.x;
    const int h = blockIdx.y;
    const int which = blockIdx.z;
    const float* __restrict__ x = which ? k : q;
    float* __restrict__ o = which ? kp : qp;

    for (int i = tid; i < M * D; i += 256) {
        int m = i >> 6, d = i & 63;
        plT[d * 132 + m] = proj[i];
    }
    const int rowbase = h * N + rblk * 32;
    for (int i = tid; i < 32 * D; i += 256) {
        int r = i >> 6, d = i & 63;
        xlT[d * 36 + r] = x[(rowbase + r) * D + d] * NORM;
    }
    __syncthreads();

    const int m0 = (tid & 31) * 4;
    const int r0 = (tid >> 5) * 4;
    float acc[4][4] = {};
#pragma unroll 8
    for (int d = 0; d < 64; d++) {
        float4 xv = *(const float4*)&xlT[d * 36 + r0];
        float4 pv = *(const float4*)&plT[d * 132 + m0];
        const float xr[4] = {xv.x, xv.y, xv.z, xv.w};
        const float pr[4] = {pv.x, pv.y, pv.z, pv.w};
#pragma unroll
        for (int ri = 0; ri < 4; ri++)
#pragma unroll
            for (int mi = 0; mi < 4; mi++) acc[ri][mi] += xr[ri] * pr[mi];
    }
    float4 sv[4];
#pragma unroll
    for (int ri = 0; ri < 4; ri++) {
        sv[ri].x = fmaxf(acc[ri][0], 0.f) + EPS;
        sv[ri].y = fmaxf(acc[ri][1], 0.f) + EPS;
        sv[ri].z = fmaxf(acc[ri][2], 0.f) + EPS;
        sv[ri].w = fmaxf(acc[ri][3], 0.f) + EPS;
        *(float4*)&o[(rowbase + r0 + ri) * M + m0] = sv[ri];
    }

    if (!which) return;

    // ---- fused per-32-row G partial: G = kp_tile^T (128m) x v_tile (64e)
    __syncthreads(); // everyone done reading plT/xlT
    float* kpl = plT; // [r][m] stride 132 (4224 floats <= 8448)
    float* vl = xlT;  // [r][e] stride 68  (2176 floats <= 2304)
#pragma unroll
    for (int ri = 0; ri < 4; ri++)
        *(float4*)&kpl[(r0 + ri) * 132 + m0] = sv[ri];
    for (int i = tid; i < 32 * D; i += 256) {
        int r = i >> 6, e = i & 63;
        vl[r * 68 + e] = v[(rowbase + r) * D + e];
    }
    __syncthreads();

    const int gb = h * 32 + rblk;
    const int mg = (tid >> 3) * 4, eg = (tid & 7) * 8;
    float ag[4][8] = {};
#pragma unroll 4
    for (int nn = 0; nn < 32; nn++) {
        float4 kv = *(const float4*)&kpl[nn * 132 + mg];
        float4 va = *(const float4*)&vl[nn * 68 + eg];
        float4 vb = *(const float4*)&vl[nn * 68 + eg + 4];
        const float kr[4] = {kv.x, kv.y, kv.z, kv.w};
        const float vr[8] = {va.x, va.y, va.z, va.w, vb.x, vb.y, vb.z, vb.w};
#pragma unroll
        for (int mi = 0; mi < 4; mi++)
#pragma unroll
            for (int ej = 0; ej < 8; ej++) ag[mi][ej] += kr[mi] * vr[ej];
    }
#pragma unroll
    for (int mi = 0; mi < 4; mi++) {
        float4 a = {ag[mi][0], ag[mi][1], ag[mi][2], ag[mi][3]};
        float4 bq = {ag[mi][4], ag[mi][5], ag[mi][6], ag[mi][7]};
        *(float4*)&Gp[(gb * M + mg + mi) * D + eg] = a;
        *(float4*)&Gp[(gb * M + mg + mi) * D + eg + 4] = bq;
    }
    if (tid < 128) {
        float ks = 0.f;
#pragma unroll 8
        for (int nn = 0; nn < 32; nn++) ks += kpl[nn * 132 + tid];
        kpart[gb * M + tid] = ks;
    }
}

// ---------------- K2: exclusive chunk-prefix of G, written over Gp seg-0.
// grid (H, 32), 256 thr: each thread owns one flat i of M*D per head.
// After this, S0 for chunk c lives at Gp[(h*32 + 4c) * M*D + i].
__global__ __launch_bounds__(256) void k_scan(float* __restrict__ Gp) {
    const int h = blockIdx.x;
    const int i = blockIdx.y * 256 + threadIdx.x;
    float run = 0.f;
#pragma unroll
    for (int c = 0; c < NC; c++) {
        const int g0 = (h * 32 + c * 4) * (M * D) + i;
        float s = Gp[g0] + Gp[g0 + M * D] + Gp[g0 + 2 * M * D] + Gp[g0 + 3 * M * D];
        Gp[g0] = run; // after all 4 reads (seg0 slot is re-read above)
        run += s;
    }
}

// ------------------------------------- K3: W = qp / Z  (in-place over qp)
// grid (64, 2), 256 thr: seg = y*2 + (tid>>7) in 0..3; serial scan 32 rows.
__global__ __launch_bounds__(256) void k_wdiv(float* __restrict__ qp,
                                              const float* __restrict__ kp,
                                              const float* __restrict__ kpart) {
    const int b = blockIdx.x;
    const int h = b >> 3, c = b & 7;
    const int seg = blockIdx.y * 2 + (threadIdx.x >> 7); // 0..3
    const int m = threadIdx.x & 127;
    float z = 0.f;
    const int send = c * 4 + seg;
    for (int s = 0; s < send; s++) z += kpart[(h * 32 + s) * M + m];
    int idx = (h * N + c * CHUNK + seg * 32) * M + m;
#pragma unroll 4
    for (int n = 0; n < 32; n++, idx += M) {
        z += kp[idx];
        qp[idx] = qp[idx] * __builtin_amdgcn_rcpf(z);
    }
}

// -------- K4 (fused): A = tril(W @ Kp^T) in LDS; out = W@S0 + A@V
// grid (64, 2 half, 2 eh), 512 thr. Phase1 (64n x 128j) duplicated per eh;
// phase2 computes 64n x 32e.
__global__ __launch_bounds__(512) void k_attn(const float* __restrict__ W,
                                              const float* __restrict__ kp,
                                              const float* __restrict__ Gp,
                                              const float* __restrict__ v,
                                              float* __restrict__ out) {
    __shared__ float AT[128 * 68]; // [j][n]
    __shared__ float Ut[32 * 68];  // [kk][n]
    __shared__ float Kt[32 * 132]; // [mm][j] phase1 / aliased Xs phase2
    float* Xs = Kt;                // [kk][e]
    const int tid = threadIdx.x;
    const int b = blockIdx.x;
    const int h = b >> 3, c = b & 7;
    const int half = blockIdx.y;
    const int eh = blockIdx.z;
    const int rowbase = h * N + c * CHUNK + half * 64;

    // ---- phase 1: A = tril(W_half @ kp_c^T) -> AT[j][n]
    {
        const int n0 = (tid >> 5) * 4;  // 16 groups x 4 = 64 n
        const int j0 = (tid & 31) * 4;  // 32 groups x 4 = 128 j
        float acc[4][4] = {};
        for (int mc = 0; mc < 4; mc++) {
            const int m0 = mc * 32;
            for (int i = tid; i < 2048; i += 512) {
                int mm = i & 31, n = i >> 5;
                Ut[mm * 68 + n] = W[(rowbase + n) * M + m0 + mm];
            }
            for (int i = tid; i < 4096; i += 512) {
                int mm = i & 31, j = i >> 5;
                Kt[mm * 132 + j] = kp[(h * N + c * CHUNK + j) * M + m0 + mm];
            }
            __syncthreads();
#pragma unroll 8
            for (int mm = 0; mm < 32; mm++) {
                float4 wa = *(const float4*)&Ut[mm * 68 + n0];
                float4 ka = *(const float4*)&Kt[mm * 132 + j0];
                const float wr[4] = {wa.x, wa.y, wa.z, wa.w};
                const float jr[4] = {ka.x, ka.y, ka.z, ka.w};
#pragma unroll
                for (int ni = 0; ni < 4; ni++)
#pragma unroll
                    for (int ji = 0; ji < 4; ji++) acc[ni][ji] += wr[ni] * jr[ji];
            }
            __syncthreads();
        }
#pragma unroll
        for (int jj = 0; jj < 4; jj++) {
            const int j = j0 + jj;
            float4 s;
            s.x = (j <= half * 64 + n0 + 0) ? acc[0][jj] : 0.f;
            s.y = (j <= half * 64 + n0 + 1) ? acc[1][jj] : 0.f;
            s.z = (j <= half * 64 + n0 + 2) ? acc[2][jj] : 0.f;
            s.w = (j <= half * 64 + n0 + 3) ? acc[3][jj] : 0.f;
            *(float4*)&AT[j * 68 + n0] = s;
        }
    }

    // ---- phase 2: out[:, eh*32 .. +32] = W @ S0 + A @ V
    {
        const int n2 = tid >> 3;                  // 64 n, 1 per group
        const int e0 = eh * 32 + (tid & 7) * 4;   // 8 groups x 4 = 32 e
        const int s0base = (h * 32 + c * 4) * (M * D);
        float acc2[4] = {};
        for (int kc = 0; kc < 8; kc++) {
            __syncthreads();
            if (kc < 4) {
                const int k0 = kc * 32;
                for (int i = tid; i < 2048; i += 512) {
                    int kk = i & 31, n = i >> 5;
                    Ut[kk * 68 + n] = W[(rowbase + n) * M + k0 + kk];
                }
                for (int i = tid; i < 2048; i += 512) {
                    int kk = i >> 6, e = i & 63;
                    Xs[kk * 68 + e] = Gp[s0base + (k0 + kk) * D + e];
                }
            } else {
                const int k0 = (kc - 4) * 32;
                for (int i = tid; i < 2048; i += 512) {
                    int kk = i >> 6, e = i & 63;
                    Xs[kk * 68 + e] = v[(h * N + c * CHUNK + k0 + kk) * D + e];
                }
            }
            __syncthreads();
            const float* ubase = (kc < 4) ? Ut : &AT[(kc - 4) * 32 * 68];
#pragma unroll 8
            for (int kk = 0; kk < 32; kk++) {
                float uu = ubase[kk * 68 + n2];
                float4 xx = *(const float4*)&Xs[kk * 68 + e0];
                acc2[0] += uu * xx.x;
                acc2[1] += uu * xx.y;
                acc2[2] += uu * xx.z;
                acc2[3] += uu * xx.w;
            }
        }
        float4 s = {acc2[0], acc2[1], acc2[2], acc2[3]};
        *(float4*)&out[(rowbase + n2) * D + e0] = s;
    }
}

extern "C" void kernel_launch(void* const* d_in, const int* in_sizes, int n_in,
                              void* d_out, int out_size, void* d_ws, size_t ws_size,
                              hipStream_t stream) {
    const float* q = (const float*)d_in[0];
    const float* k = (const float*)d_in[1];
    const float* v = (const float*)d_in[2];
    const float* proj = (const float*)d_in[3];
    float* out = (float*)d_out;

    // workspace (floats): qp 1M + kp 1M + kpart 32K + Gp 2M = 16.5 MB
    float* ws = (float*)d_ws;
    float* qp = ws;                     // H*N*M (becomes W after k_wdiv)
    float* kp = qp + H * N * M;         // H*N*M
    float* kpart = kp + H * N * M;      // H*32*M
    float* Gp = kpart + H * 32 * M;     // H*32*M*D (seg-0 slots become S0)

    k_projg<<<dim3(N / 32, H, 2), 256, 0, stream>>>(q, k, proj, v, qp, kp, Gp, kpart);
    k_scan<<<dim3(H, 32), 256, 0, stream>>>(Gp);
    k_wdiv<<<dim3(H * NC, 2), 256, 0, stream>>>(qp, kp, kpart);
    k_attn<<<dim3(H * NC, 2, 2), 512, 0, stream>>>(qp, kp, Gp, v, out);
}